// Round 1
// baseline (1564.212 us; speedup 1.0000x reference)
//
#include <hip/hip_runtime.h>
#include <hip/hip_bf16.h>
#include <math.h>

typedef unsigned short ushort_t;
typedef __attribute__((ext_vector_type(8))) short short8;
typedef __attribute__((ext_vector_type(4))) float f32x4;

typedef __attribute__((address_space(3))) void lds_void;
typedef __attribute__((address_space(1))) void gbl_void;

#define IGNORE_INDEX (-100)

__device__ __forceinline__ ushort_t f32_to_bf16_rne(float f) {
    union { float f; unsigned u; } v; v.f = f;
    unsigned r = v.u + 0x7fffu + ((v.u >> 16) & 1u);
    return (ushort_t)(r >> 16);
}

// ---------------- fp32 -> bf16 conversion (memory-bound) ----------------
__global__ __launch_bounds__(256) void cvt_f32_bf16(const float* __restrict__ in,
                                                    ushort_t* __restrict__ out,
                                                    long n) {
    long i = (long)blockIdx.x * blockDim.x + threadIdx.x;
    long stride = (long)gridDim.x * blockDim.x;
    for (long j = i * 4; j + 3 < n; j += stride * 4) {
        float4 f = *(const float4*)(in + j);
        ushort_t o0 = f32_to_bf16_rne(f.x);
        ushort_t o1 = f32_to_bf16_rne(f.y);
        ushort_t o2 = f32_to_bf16_rne(f.z);
        ushort_t o3 = f32_to_bf16_rne(f.w);
        ushort4 o; o.x = o0; o.y = o1; o.z = o2; o.w = o3;
        *(ushort4*)(out + j) = o;
    }
}

// ---------------- fused bf16 GEMM tile + online LSE partials ----------------
// Tile: BM=128 rows of x, BN=128 vocab cols, BK=64. 256 threads = 4 waves (2x2).
// LDS layout: [128 rows][8 chunks of 16B], chunk index XOR-swizzled by (row&7)
// so global_load_lds (lane-ordered dest) and ds_read_b128 (per-quad frag reads)
// are both conflict-free (2-way aliasing only, free per m136).
__global__ __launch_bounds__(256) void gemm_lse_partial(
    const ushort_t* __restrict__ Abf,   // [N][H] bf16
    const ushort_t* __restrict__ Bbf,   // [V][H] bf16
    float2* __restrict__ partials,      // [N][VT]  (m, sumexp)
    int H, int V, int VT)
{
    constexpr int BM = 128, BK = 64;
    __shared__ ushort_t As[BM * BK];   // 16 KB
    __shared__ ushort_t Bs[BM * BK];   // 16 KB

    const int tid  = threadIdx.x;
    const int w    = tid >> 6;
    const int lane = tid & 63;
    const int wm   = w >> 1, wn = w & 1;
    const int q    = lane >> 4, rowi = lane & 15;

    const int mBase = blockIdx.x * BM;
    const int vTile = blockIdx.y;
    const int vBase = vTile * BM;

    // staging: each wave stages 4 chunks of 1024B for A and B.
    const int rsub = lane >> 3;          // 0..7 row within 8-row chunk
    const int csub = lane & 7;           // 16B-chunk column 0..7
    const int sch  = csub ^ rsub;        // XOR-swizzled source chunk

    int aRow[4], bRow[4];
#pragma unroll
    for (int c = 0; c < 4; ++c) {
        int chunk = w * 4 + c;
        int r = chunk * 8 + rsub;        // 0..127
        aRow[c] = mBase + r;
        int vr = vBase + r;
        bRow[c] = (vr < V) ? vr : (V - 1);
    }

    f32x4 acc[4][4];
#pragma unroll
    for (int i = 0; i < 4; ++i)
#pragma unroll
        for (int j = 0; j < 4; ++j) acc[i][j] = (f32x4)(0.0f);

    const size_t Hs = (size_t)H;
    for (int k0 = 0; k0 < H; k0 += BK) {
#pragma unroll
        for (int c = 0; c < 4; ++c) {
            int chunk = w * 4 + c;
            const ushort_t* gA = Abf + (size_t)aRow[c] * Hs + k0 + sch * 8;
            const ushort_t* gB = Bbf + (size_t)bRow[c] * Hs + k0 + sch * 8;
            __builtin_amdgcn_global_load_lds((gbl_void*)gA, (lds_void*)(As + chunk * 512), 16, 0, 0);
            __builtin_amdgcn_global_load_lds((gbl_void*)gB, (lds_void*)(Bs + chunk * 512), 16, 0, 0);
        }
        __syncthreads();

#pragma unroll
        for (int ks = 0; ks < 2; ++ks) {
            short8 af[4], bf[4];
#pragma unroll
            for (int i = 0; i < 4; ++i) {
                int ar = wm * 64 + i * 16 + rowi;
                int ch = (ks * 4 + q) ^ (rowi & 7);
                af[i] = *(const short8*)(As + ar * 64 + ch * 8);
                int br = wn * 64 + i * 16 + rowi;
                bf[i] = *(const short8*)(Bs + br * 64 + ch * 8);
            }
#pragma unroll
            for (int i = 0; i < 4; ++i)
#pragma unroll
                for (int j = 0; j < 4; ++j)
                    acc[i][j] = __builtin_amdgcn_mfma_f32_16x16x32_bf16(af[i], bf[j], acc[i][j], 0, 0, 0);
        }
        __syncthreads();
    }

    // ---- online-softmax partial per row of the 128x128 tile ----
    // C/D layout (verified m89/m91): col = lane&15, row = q*4 + reg.
    bool valj[4];
#pragma unroll
    for (int j = 0; j < 4; ++j)
        valj[j] = (vBase + wn * 64 + j * 16 + rowi) < V;

    float2* red = (float2*)As;   // reuse LDS: [128 rows][2 wave-halves]

#pragma unroll
    for (int i = 0; i < 4; ++i) {
#pragma unroll
        for (int r = 0; r < 4; ++r) {
            float m = -INFINITY;
#pragma unroll
            for (int j = 0; j < 4; ++j) {
                float v = acc[i][j][r];
                if (valj[j]) m = fmaxf(m, v);
            }
#pragma unroll
            for (int o = 1; o < 16; o <<= 1)
                m = fmaxf(m, __shfl_xor(m, o, 64));
            float s = 0.0f;
#pragma unroll
            for (int j = 0; j < 4; ++j) {
                float v = acc[i][j][r];
                if (valj[j]) s += __expf(v - m);
            }
#pragma unroll
            for (int o = 1; o < 16; o <<= 1)
                s += __shfl_xor(s, o, 64);
            if (rowi == 0) {
                int row = wm * 64 + i * 16 + q * 4 + r;
                red[row * 2 + wn] = make_float2(m, s);
            }
        }
    }
    __syncthreads();

    if (tid < BM) {
        float2 p0 = red[tid * 2 + 0];
        float2 p1 = red[tid * 2 + 1];
        float m = fmaxf(p0.x, p1.x);
        float s = p0.y * __expf(p0.x - m) + p1.y * __expf(p1.x - m);
        partials[(size_t)(mBase + tid) * VT + vTile] = make_float2(m, s);
    }
}

// ---------------- per-row: merge partials -> LSE, fp32 label dot ----------------
__global__ __launch_bounds__(256) void row_final(
    const float* __restrict__ x,      // [N][H] fp32
    const float* __restrict__ W,      // [V][H] fp32
    const int* __restrict__ y,        // [N]
    const float2* __restrict__ partials, // [N][VT]
    float* __restrict__ nll, float* __restrict__ valid,
    int H, int V, int VT)
{
    const int n = blockIdx.x;
    const int t = threadIdx.x;
    const int yn = y[n];
    const bool ok = (yn != IGNORE_INDEX);

    // label logit in full fp32
    float dsum = 0.0f;
    if (ok) {
        int cy = yn; if (cy < 0) cy = 0; if (cy >= V) cy = V - 1;
        const float4* xr = (const float4*)(x + (size_t)n * H);
        const float4* wr = (const float4*)(W + (size_t)cy * H);
        int nf4 = H >> 2;
        for (int i = t; i < nf4; i += 256) {
            float4 a = xr[i], b = wr[i];
            dsum += a.x * b.x + a.y * b.y + a.z * b.z + a.w * b.w;
        }
    }

    // merge this row's LSE partials
    float m = -INFINITY, s = 0.0f;
    const float2* pr = partials + (size_t)n * VT;
    for (int i = t; i < VT; i += 256) {
        float2 p = pr[i];
        float nm = fmaxf(m, p.x);
        s = s * __expf(m - nm) + p.y * __expf(p.x - nm);
        m = nm;
    }

    __shared__ float rm[256], rs[256], rd[256];
    rm[t] = m; rs[t] = s; rd[t] = dsum;
    __syncthreads();
    for (int o = 128; o > 0; o >>= 1) {
        if (t < o) {
            float m2 = rm[t + o], s2 = rs[t + o];
            float nm = fmaxf(rm[t], m2);
            rs[t] = rs[t] * __expf(rm[t] - nm) + s2 * __expf(m2 - nm);
            rm[t] = nm;
            rd[t] += rd[t + o];
        }
        __syncthreads();
    }
    if (t == 0) {
        float lse = rm[0] + __logf(rs[0]);
        nll[n]   = ok ? (lse - rd[0]) : 0.0f;
        valid[n] = ok ? 1.0f : 0.0f;
    }
}

// ---------------- final: loss = sum(nll) / max(sum(valid), 1) ----------------
__global__ __launch_bounds__(1024) void final_loss(
    const float* __restrict__ nll, const float* __restrict__ valid,
    float* __restrict__ out, int n)
{
    __shared__ float ss[1024], sv[1024];
    const int t = threadIdx.x;
    float a = 0.0f, b = 0.0f;
    for (int i = t; i < n; i += 1024) { a += nll[i]; b += valid[i]; }
    ss[t] = a; sv[t] = b;
    __syncthreads();
    for (int o = 512; o > 0; o >>= 1) {
        if (t < o) { ss[t] += ss[t + o]; sv[t] += sv[t + o]; }
        __syncthreads();
    }
    if (t == 0) out[0] = ss[0] / fmaxf(sv[0], 1.0f);
}

extern "C" void kernel_launch(void* const* d_in, const int* in_sizes, int n_in,
                              void* d_out, int out_size, void* d_ws, size_t ws_size,
                              hipStream_t stream) {
    const float* x = (const float*)d_in[0];
    const float* W = (const float*)d_in[1];
    const int*   y = (const int*)d_in[2];

    const long xsz = in_sizes[0];            // N*H
    const long wsz = in_sizes[1];            // V*H
    const int  N   = in_sizes[2];
    const int  H   = (int)(xsz / N);         // 2048
    const int  V   = (int)(wsz / H);         // 50257
    const int  VT  = (V + 127) / 128;        // 393
    const int  MT  = N / 128;                // 32

    char* ws = (char*)d_ws;
    size_t off = 0;
    ushort_t* Wbf = (ushort_t*)(ws + off); off += (size_t)wsz * 2; off = (off + 255) & ~(size_t)255;
    ushort_t* Xbf = (ushort_t*)(ws + off); off += (size_t)xsz * 2; off = (off + 255) & ~(size_t)255;
    float2* partials = (float2*)(ws + off); off += (size_t)N * VT * sizeof(float2); off = (off + 255) & ~(size_t)255;
    float* nll   = (float*)(ws + off); off += (size_t)N * 4;
    float* valid = (float*)(ws + off); off += (size_t)N * 4;

    cvt_f32_bf16<<<4096, 256, 0, stream>>>(W, Wbf, wsz);
    cvt_f32_bf16<<<512, 256, 0, stream>>>(x, Xbf, xsz);

    dim3 grid(MT, VT);   // x = mTile (fast) -> consecutive blocks share the W tile (L2 reuse)
    gemm_lse_partial<<<grid, 256, 0, stream>>>(Xbf, Wbf, partials, H, V, VT);

    row_final<<<N, 256, 0, stream>>>(x, W, y, partials, nll, valid, H, V, VT);
    final_loss<<<1, 1024, 0, stream>>>(nll, valid, (float*)d_out, N);
}

// Round 2
// 1210.283 us; speedup vs baseline: 1.2924x; 1.2924x over previous
//
#include <hip/hip_runtime.h>
#include <hip/hip_bf16.h>
#include <math.h>

typedef unsigned char  u8;
typedef unsigned int   u32;
typedef __attribute__((ext_vector_type(8)))  int   int8v;
typedef __attribute__((ext_vector_type(16))) float f32x16;

typedef __attribute__((address_space(3))) void lds_void;
typedef __attribute__((address_space(1))) void gbl_void;

#define IGNORE_INDEX (-100)

// ---------------- fp32 -> OCP e4m3 with explicit RNE ----------------
__device__ __forceinline__ u8 f32_to_e4m3(float f) {
    union { float f; u32 u; } v; v.f = f;
    u32 s  = (v.u >> 24) & 0x80u;
    u32 au = v.u & 0x7FFFFFFFu;
    float a = __uint_as_float(au);
    if (a >= 448.0f) return (u8)(s | 0x7E);          // clamp to max normal
    int e = (int)(au >> 23) - 127;
    if (e >= -6) {
        u32 m    = au & 0x7FFFFFu;
        u32 keep = m >> 20;
        u32 rest = m & 0xFFFFFu;
        keep += (rest > 0x80000u) || (rest == 0x80000u && (keep & 1u));
        u32 code = ((u32)(e + 7) << 3) + keep;        // mantissa carry bumps exponent
        if (code > 0x7E) code = 0x7E;
        return (u8)(s | code);
    } else {
        int q = (int)rintf(a * 512.0f);               // subnormal quantum 2^-9 (RNE)
        return (u8)(s | (u32)q);                      // q==8 lands on min-normal encoding
    }
}

// ---------------- fp32 -> fp8 conversion (memory-bound), pre-scaled ----------------
__global__ __launch_bounds__(256) void cvt_f32_fp8(const float* __restrict__ in,
                                                   u8* __restrict__ out,
                                                   float scale, long n) {
    long i = (long)blockIdx.x * blockDim.x + threadIdx.x;
    long stride = (long)gridDim.x * blockDim.x;
    for (long j = i * 16; j + 15 < n; j += stride * 16) {
        u8 tmp[16];
#pragma unroll
        for (int t = 0; t < 4; ++t) {
            float4 f = *(const float4*)(in + j + t * 4);
            tmp[t * 4 + 0] = f32_to_e4m3(f.x * scale);
            tmp[t * 4 + 1] = f32_to_e4m3(f.y * scale);
            tmp[t * 4 + 2] = f32_to_e4m3(f.z * scale);
            tmp[t * 4 + 3] = f32_to_e4m3(f.w * scale);
        }
        *(int4*)(out + j) = *(const int4*)tmp;
    }
}

// ---------------- fused MX-fp8 GEMM tile + online LSE partials ----------------
// BM=128 rows, BN=128 cols, BK=128 (bytes==elems). 256 threads = 4 waves (2x2),
// each wave computes 64x64 via 2x2 frags of mfma_scale_f32_32x32x64_f8f6f4.
// Uniform E8M0 scales: A holds x*8 (scale 2^-3), B holds W*16 (scale 2^-4) --
// keeps both operands out of e4m3 subnormal range AND makes the per-lane
// scale-to-block mapping irrelevant.
// LDS: [128 rows][8 chunks of 16B], chunk XOR-swizzled by (row&7).
__global__ __launch_bounds__(256) void gemm_lse_partial(
    const u8* __restrict__ A8,      // [N][H] fp8 (x*8)
    const u8* __restrict__ B8,      // [V][H] fp8 (W*16)
    float2* __restrict__ partials,  // [N][VT]  (m, sumexp)
    int H, int V, int VT)
{
    constexpr int BM = 128, BKB = 128;
    __shared__ __align__(16) u8 As[BM * BKB];   // 16 KB
    __shared__ __align__(16) u8 Bs[BM * BKB];   // 16 KB

    const int tid  = threadIdx.x;
    const int w    = tid >> 6;
    const int lane = tid & 63;
    const int wm   = w >> 1, wn = w & 1;
    const int half = lane >> 5;          // k-half of the 64-K mfma step
    const int ln32 = lane & 31;

    const int mBase = blockIdx.x * BM;
    const int vTile = blockIdx.y;
    const int vBase = vTile * BM;

    // staging: each wave stages 4 bands of 8 rows; lane -> (row rsub, chunk csub)
    const int rsub = lane >> 3;          // 0..7 row within band
    const int csub = lane & 7;           // dest chunk 0..7
    const int sch  = csub ^ rsub;        // XOR-swizzled SOURCE chunk

    int aRow[4], bRow[4];
#pragma unroll
    for (int c = 0; c < 4; ++c) {
        int band = w * 4 + c;
        int r = band * 8 + rsub;         // 0..127
        aRow[c] = mBase + r;
        int vr = vBase + r;
        bRow[c] = (vr < V) ? vr : (V - 1);
    }

    f32x16 acc[2][2];
#pragma unroll
    for (int i = 0; i < 2; ++i)
#pragma unroll
        for (int j = 0; j < 2; ++j)
#pragma unroll
            for (int r = 0; r < 16; ++r) acc[i][j][r] = 0.0f;

    const int scaleA = 0x7C7C7C7C;  // E8M0 124 = 2^-3 (undo x*8)
    const int scaleB = 0x7B7B7B7B;  // E8M0 123 = 2^-4 (undo W*16)

    const size_t Hs = (size_t)H;
    for (int k0 = 0; k0 < H; k0 += BKB) {
#pragma unroll
        for (int c = 0; c < 4; ++c) {
            int band = w * 4 + c;
            const u8* gA = A8 + (size_t)aRow[c] * Hs + k0 + sch * 16;
            const u8* gB = B8 + (size_t)bRow[c] * Hs + k0 + sch * 16;
            __builtin_amdgcn_global_load_lds((gbl_void*)gA, (lds_void*)(As + band * 1024), 16, 0, 0);
            __builtin_amdgcn_global_load_lds((gbl_void*)gB, (lds_void*)(Bs + band * 1024), 16, 0, 0);
        }
        __syncthreads();

#pragma unroll
        for (int ks = 0; ks < 2; ++ks) {
            int8v af[2], bf[2];
            const int c0 = ks * 4 + half * 2;    // even chunk index
#pragma unroll
            for (int i = 0; i < 2; ++i) {
                int ar = wm * 64 + i * 32 + ln32;
                int sw = ar & 7;
                int4 lo = *(const int4*)(As + ar * 128 + ((c0    ) ^ sw) * 16);
                int4 hi = *(const int4*)(As + ar * 128 + ((c0 + 1) ^ sw) * 16);
                int8v a; a[0]=lo.x; a[1]=lo.y; a[2]=lo.z; a[3]=lo.w;
                         a[4]=hi.x; a[5]=hi.y; a[6]=hi.z; a[7]=hi.w;
                af[i] = a;
                int br = wn * 64 + i * 32 + ln32;
                sw = br & 7;
                lo = *(const int4*)(Bs + br * 128 + ((c0    ) ^ sw) * 16);
                hi = *(const int4*)(Bs + br * 128 + ((c0 + 1) ^ sw) * 16);
                int8v b; b[0]=lo.x; b[1]=lo.y; b[2]=lo.z; b[3]=lo.w;
                         b[4]=hi.x; b[5]=hi.y; b[6]=hi.z; b[7]=hi.w;
                bf[i] = b;
            }
#pragma unroll
            for (int i = 0; i < 2; ++i)
#pragma unroll
                for (int j = 0; j < 2; ++j)
                    acc[i][j] = __builtin_amdgcn_mfma_scale_f32_32x32x64_f8f6f4(
                        af[i], bf[j], acc[i][j], 0, 0, 0, scaleA, 0, scaleB);
        }
        __syncthreads();
    }

    // ---- online-softmax partial per row of the 128x128 tile ----
    // C/D 32x32 layout (m74/m101, fmt-independent): col=lane&31,
    // row=(reg&3)+8*(reg>>2)+4*(lane>>5).
    bool vj[2];
#pragma unroll
    for (int j = 0; j < 2; ++j)
        vj[j] = (vBase + wn * 64 + j * 32 + ln32) < V;

    float2* red = (float2*)As;   // reuse LDS: [128 rows][2 wave-halves]

#pragma unroll
    for (int i = 0; i < 2; ++i) {
#pragma unroll
        for (int r = 0; r < 16; ++r) {
            float v0 = vj[0] ? acc[i][0][r] : -INFINITY;
            float v1 = vj[1] ? acc[i][1][r] : -INFINITY;
            float m = fmaxf(v0, v1);
#pragma unroll
            for (int o = 1; o < 32; o <<= 1)
                m = fmaxf(m, __shfl_xor(m, o, 64));
            float s = 0.0f;
            if (vj[0]) s += __expf(acc[i][0][r] - m);
            if (vj[1]) s += __expf(acc[i][1][r] - m);
#pragma unroll
            for (int o = 1; o < 32; o <<= 1)
                s += __shfl_xor(s, o, 64);
            if (ln32 == 0) {
                int row = wm * 64 + i * 32 + (r & 3) + 8 * (r >> 2) + 4 * half;
                red[row * 2 + wn] = make_float2(m, s);
            }
        }
    }
    __syncthreads();

    if (tid < BM) {
        float2 p0 = red[tid * 2 + 0];
        float2 p1 = red[tid * 2 + 1];
        float m = fmaxf(p0.x, p1.x);
        float s = p0.y * __expf(p0.x - m) + p1.y * __expf(p1.x - m);
        partials[(size_t)(mBase + tid) * VT + vTile] = make_float2(m, s);
    }
}

// ---------------- per-row: merge partials -> LSE, fp32 label dot ----------------
__global__ __launch_bounds__(256) void row_final(
    const float* __restrict__ x,      // [N][H] fp32
    const float* __restrict__ W,      // [V][H] fp32
    const int* __restrict__ y,        // [N]
    const float2* __restrict__ partials, // [N][VT]
    float* __restrict__ nll, float* __restrict__ valid,
    int H, int V, int VT)
{
    const int n = blockIdx.x;
    const int t = threadIdx.x;
    const int yn = y[n];
    const bool ok = (yn != IGNORE_INDEX);

    // label logit in full fp32
    float dsum = 0.0f;
    if (ok) {
        int cy = yn; if (cy < 0) cy = 0; if (cy >= V) cy = V - 1;
        const float4* xr = (const float4*)(x + (size_t)n * H);
        const float4* wr = (const float4*)(W + (size_t)cy * H);
        int nf4 = H >> 2;
        for (int i = t; i < nf4; i += 256) {
            float4 a = xr[i], b = wr[i];
            dsum += a.x * b.x + a.y * b.y + a.z * b.z + a.w * b.w;
        }
    }

    // merge this row's LSE partials
    float m = -INFINITY, s = 0.0f;
    const float2* pr = partials + (size_t)n * VT;
    for (int i = t; i < VT; i += 256) {
        float2 p = pr[i];
        float nm = fmaxf(m, p.x);
        s = s * __expf(m - nm) + p.y * __expf(p.x - nm);
        m = nm;
    }

    __shared__ float rm[256], rs[256], rd[256];
    rm[t] = m; rs[t] = s; rd[t] = dsum;
    __syncthreads();
    for (int o = 128; o > 0; o >>= 1) {
        if (t < o) {
            float m2 = rm[t + o], s2 = rs[t + o];
            float nm = fmaxf(rm[t], m2);
            rs[t] = rs[t] * __expf(rm[t] - nm) + s2 * __expf(m2 - nm);
            rm[t] = nm;
            rd[t] += rd[t + o];
        }
        __syncthreads();
    }
    if (t == 0) {
        float lse = rm[0] + __logf(rs[0]);
        nll[n]   = ok ? (lse - rd[0]) : 0.0f;
        valid[n] = ok ? 1.0f : 0.0f;
    }
}

// ---------------- final: loss = sum(nll) / max(sum(valid), 1) ----------------
__global__ __launch_bounds__(1024) void final_loss(
    const float* __restrict__ nll, const float* __restrict__ valid,
    float* __restrict__ out, int n)
{
    __shared__ float ss[1024], sv[1024];
    const int t = threadIdx.x;
    float a = 0.0f, b = 0.0f;
    for (int i = t; i < n; i += 1024) { a += nll[i]; b += valid[i]; }
    ss[t] = a; sv[t] = b;
    __syncthreads();
    for (int o = 512; o > 0; o >>= 1) {
        if (t < o) { ss[t] += ss[t + o]; sv[t] += sv[t + o]; }
        __syncthreads();
    }
    if (t == 0) out[0] = ss[0] / fmaxf(sv[0], 1.0f);
}

extern "C" void kernel_launch(void* const* d_in, const int* in_sizes, int n_in,
                              void* d_out, int out_size, void* d_ws, size_t ws_size,
                              hipStream_t stream) {
    const float* x = (const float*)d_in[0];
    const float* W = (const float*)d_in[1];
    const int*   y = (const int*)d_in[2];

    const long xsz = in_sizes[0];            // N*H
    const long wsz = in_sizes[1];            // V*H
    const int  N   = in_sizes[2];
    const int  H   = (int)(xsz / N);         // 2048
    const int  V   = (int)(wsz / H);         // 50257
    const int  VT  = (V + 127) / 128;        // 393
    const int  MT  = N / 128;                // 32

    char* ws = (char*)d_ws;
    size_t off = 0;
    u8* Wf8 = (u8*)(ws + off); off += (size_t)wsz; off = (off + 255) & ~(size_t)255;
    u8* Xf8 = (u8*)(ws + off); off += (size_t)xsz; off = (off + 255) & ~(size_t)255;
    float2* partials = (float2*)(ws + off); off += (size_t)N * VT * sizeof(float2); off = (off + 255) & ~(size_t)255;
    float* nll   = (float*)(ws + off); off += (size_t)N * 4;
    float* valid = (float*)(ws + off); off += (size_t)N * 4;

    int wBlocks = (int)((wsz / 16 + 255) / 256);
    int xBlocks = (int)((xsz / 16 + 255) / 256);
    cvt_f32_fp8<<<wBlocks, 256, 0, stream>>>(W, Wf8, 16.0f, wsz);
    cvt_f32_fp8<<<xBlocks, 256, 0, stream>>>(x, Xf8, 8.0f, xsz);

    dim3 grid(MT, VT);   // mTile fast -> consecutive blocks share the W tile (L2 reuse)
    gemm_lse_partial<<<grid, 256, 0, stream>>>(Xf8, Wf8, partials, H, V, VT);

    row_final<<<N, 256, 0, stream>>>(x, W, y, partials, nll, valid, H, V, VT);
    final_loss<<<1, 1024, 0, stream>>>(nll, valid, (float*)d_out, N);
}